// Round 1
// baseline (621.744 us; speedup 1.0000x reference)
//
#include <hip/hip_runtime.h>
#include <math.h>

// Problem constants
#define CH   64     // C
#define FD   128    // F
#define HS   64     // half-res spatial (H/2 = W/2)
#define FS   128    // full-res spatial
#define NB   8      // B
#define NCTX 3      // N

// workspace layout (in floats)
#define WS_WQ  0                          // Wq[C][F]  = Wc^T * Wf
#define WS_BQ  (WS_WQ + CH*FD)            // bq[C]     = Wc^T * bf
#define WS_QT  (WS_BQ + CH)               // qt [B][C][HS][HS]
#define WS_VAL (WS_QT + NB*CH*HS*HS)      // values conv output [B][C][HS][HS]
#define WS_L3  (WS_VAL + NB*CH*HS*HS)     // mainstream-slot logit [B][HS][HS]
// total = 8192+64+2097152+2097152+32768 floats = ~16.2 MiB

// ---------------------------------------------------------------------------
// Kernel 1: fold Wc onto the query side.
// Wq[c][f] = sum_d Wc[d][c] * Wf[d][f];  bq[c] = sum_d Wc[d][c] * bf[d]
// (bc * q term is n-independent -> cancels in softmax; dropped entirely)
// ---------------------------------------------------------------------------
__global__ __launch_bounds__(256) void prep_weights(
    const float* __restrict__ Wc, const float* __restrict__ Wf,
    const float* __restrict__ bf, float* __restrict__ ws) {
  int i = blockIdx.x * 256 + threadIdx.x;   // 0..8191
  int c = i >> 7, f = i & 127;
  float acc = 0.f;
#pragma unroll 8
  for (int d = 0; d < CH; ++d)
    acc = fmaf(Wc[d * CH + c], Wf[d * FD + f], acc);
  ws[WS_WQ + i] = acc;
  if (i < CH) {
    float b = 0.f;
#pragma unroll 8
    for (int d = 0; d < CH; ++d) b = fmaf(Wc[d * CH + i], bf[d], b);
    ws[WS_BQ + i] = b;
  }
}

// ---------------------------------------------------------------------------
// Kernel 2 (half-res): qt = Wq*m + bq ; keys = Wk*m + bk ; logit3 = qt . keys
// One block per (b, row). 4 waves; wave w handles channels [16w, 16w+16).
// Weight indices are wave-uniform (readfirstlane) -> scalar loads.
// ---------------------------------------------------------------------------
__global__ __launch_bounds__(256) void half_qt_kernel(
    const float* __restrict__ m, const float* __restrict__ Wk,
    const float* __restrict__ bk, float* __restrict__ ws) {
  const int b = blockIdx.x >> 6;
  const int y = blockIdx.x & 63;
  const int x = threadIdx.x & 63;
  const int wave = __builtin_amdgcn_readfirstlane(threadIdx.x >> 6);
  const int c0 = wave * 16;

  const float* Wq = ws + WS_WQ;
  const float* bq = ws + WS_BQ;

  float qa[16], ka[16];
#pragma unroll
  for (int j = 0; j < 16; ++j) { qa[j] = bq[c0 + j]; ka[j] = bk[c0 + j]; }

  const float* mp = m + ((b * FD) * HS + y) * HS + x;  // + f*HS*HS
  for (int fc = 0; fc < FD; fc += 8) {
    float mv[8];
#pragma unroll
    for (int u = 0; u < 8; ++u) mv[u] = mp[(fc + u) * HS * HS];
#pragma unroll
    for (int j = 0; j < 16; ++j) {
      const float* wq = Wq + (c0 + j) * FD + fc;
      const float* wk = Wk + (c0 + j) * FD + fc;
#pragma unroll
      for (int u = 0; u < 8; ++u) {
        qa[j] = fmaf(wq[u], mv[u], qa[j]);
        ka[j] = fmaf(wk[u], mv[u], ka[j]);
      }
    }
  }

  // write qt, layout [b][c][y][x]
  float* qt = ws + WS_QT;
#pragma unroll
  for (int j = 0; j < 16; ++j)
    qt[((b * CH + c0 + j) * HS + y) * HS + x] = qa[j];

  // logit3 partial dot, reduce across the 4 channel-group waves via LDS
  float part = 0.f;
#pragma unroll
  for (int j = 0; j < 16; ++j) part = fmaf(qa[j], ka[j], part);
  __shared__ float red[4][64];
  red[wave][x] = part;
  __syncthreads();
  if (threadIdx.x < 64) {
    float l3 = red[0][x] + red[1][x] + red[2][x] + red[3][x];
    ws[WS_L3 + (b * HS + y) * HS + x] = l3;
  }
}

// ---------------------------------------------------------------------------
// Kernel 3 (half-res): values = conv3x3(mainstream, Vw) + Vb
// Same block/wave structure as kernel 2. Direct conv: per f, load 9-neighborhood
// into VGPRs (zero-padded via mask), 16 channels x 9 taps of scalar-weight FMAs.
// ---------------------------------------------------------------------------
__global__ __launch_bounds__(256) void half_conv_kernel(
    const float* __restrict__ m, const float* __restrict__ Vw,
    const float* __restrict__ Vb, float* __restrict__ ws) {
  const int b = blockIdx.x >> 6;
  const int y = blockIdx.x & 63;
  const int x = threadIdx.x & 63;
  const int wave = __builtin_amdgcn_readfirstlane(threadIdx.x >> 6);
  const int c0 = wave * 16;

  float va[16];
#pragma unroll
  for (int j = 0; j < 16; ++j) va[j] = Vb[c0 + j];

  // neighborhood offsets + zero-pad masks (constant over f)
  int offs[9];
  float msk[9];
#pragma unroll
  for (int dy = -1; dy <= 1; ++dy) {
#pragma unroll
    for (int dx = -1; dx <= 1; ++dx) {
      int t = (dy + 1) * 3 + (dx + 1);
      int yy = y + dy, xx = x + dx;
      bool ok = (yy >= 0 && yy < HS && xx >= 0 && xx < HS);
      offs[t] = ok ? (yy * HS + xx) : 0;
      msk[t] = ok ? 1.f : 0.f;
    }
  }

  const float* mb = m + (size_t)b * FD * HS * HS;
  for (int f = 0; f < FD; ++f) {
    const float* mf = mb + f * HS * HS;
    float nv[9];
#pragma unroll
    for (int t = 0; t < 9; ++t) nv[t] = mf[offs[t]] * msk[t];
#pragma unroll
    for (int j = 0; j < 16; ++j) {
      const float* vw = Vw + ((c0 + j) * FD + f) * 9;  // wave-uniform -> s_load
#pragma unroll
      for (int k = 0; k < 9; ++k) va[j] = fmaf(vw[k], nv[k], va[j]);
    }
  }

  float* val = ws + WS_VAL;
#pragma unroll
  for (int j = 0; j < 16; ++j)
    val[((b * CH + c0 + j) * HS + y) * HS + x] = va[j];
}

// ---------------------------------------------------------------------------
// Kernel 4 (full-res): logits -> softmax -> weighted sum. Thread per pixel.
// logit_n = ctx[b,n,:,h,w] . qt[b,:,h/2,w/2]  (n<3),  logit_3 from ws.
// out[c] = a3*val_up[c] + sum_n a_n*ctx[n][c]
// ---------------------------------------------------------------------------
__global__ __launch_bounds__(256) void fullres_kernel(
    const float* __restrict__ ctx, const float* __restrict__ ws,
    float* __restrict__ out) {
  const int w = threadIdx.x;                        // 0..127
  const int hrow = blockIdx.x * 2 + threadIdx.y;    // 0..127
  const int b = blockIdx.y;
  const int h2 = hrow >> 1, w2 = w >> 1;

  const float* qt = ws + WS_QT + ((b * CH) * HS + h2) * HS + w2;  // + c*HS*HS
  const float* cb = ctx + (((size_t)b * NCTX * CH) * FS + hrow) * FS + w;
  const int cs = FS * FS;          // channel stride 16384
  const int ns = CH * FS * FS;     // context stride 1048576

  float l0 = 0.f, l1 = 0.f, l2 = 0.f;
#pragma unroll 4
  for (int c = 0; c < CH; ++c) {
    float q = qt[c * HS * HS];
    l0 = fmaf(cb[c * cs], q, l0);
    l1 = fmaf(cb[ns + c * cs], q, l1);
    l2 = fmaf(cb[2 * ns + c * cs], q, l2);
  }
  float l3 = ws[WS_L3 + (b * HS + h2) * HS + w2];

  float mx = fmaxf(fmaxf(l0, l1), fmaxf(l2, l3));
  float e0 = __expf(l0 - mx), e1 = __expf(l1 - mx);
  float e2 = __expf(l2 - mx), e3 = __expf(l3 - mx);
  float inv = 1.f / (e0 + e1 + e2 + e3);
  float a0 = e0 * inv, a1 = e1 * inv, a2 = e2 * inv, a3 = e3 * inv;

  const float* val = ws + WS_VAL + ((b * CH) * HS + h2) * HS + w2;
  float* op = out + ((size_t)(b * CH) * FS + hrow) * FS + w;
#pragma unroll 4
  for (int c = 0; c < CH; ++c) {
    float o = a3 * val[c * HS * HS];
    o = fmaf(a0, cb[c * cs], o);
    o = fmaf(a1, cb[ns + c * cs], o);
    o = fmaf(a2, cb[2 * ns + c * cs], o);
    op[c * cs] = o;
  }
}

// ---------------------------------------------------------------------------
extern "C" void kernel_launch(void* const* d_in, const int* in_sizes, int n_in,
                              void* d_out, int out_size, void* d_ws, size_t ws_size,
                              hipStream_t stream) {
  const float* ctx = (const float*)d_in[0];  // [B,N,C,H,W]
  const float* ms  = (const float*)d_in[1];  // [B,F,HS,HS]
  const float* Wc  = (const float*)d_in[2];  // [C,C]
  // d_in[3] = bc : cancels in softmax, unused
  const float* Wf  = (const float*)d_in[4];  // [C,F]
  const float* bf  = (const float*)d_in[5];  // [C]
  const float* Wk  = (const float*)d_in[6];  // [C,F]
  const float* bk  = (const float*)d_in[7];  // [C]
  const float* Vw  = (const float*)d_in[8];  // [C,F,3,3]
  const float* Vb  = (const float*)d_in[9];  // [C]
  float* ws  = (float*)d_ws;
  float* out = (float*)d_out;

  prep_weights<<<32, 256, 0, stream>>>(Wc, Wf, bf, ws);
  half_qt_kernel<<<NB * HS, 256, 0, stream>>>(ms, Wk, bk, ws);
  half_conv_kernel<<<NB * HS, 256, 0, stream>>>(ms, Vw, Vb, ws);
  fullres_kernel<<<dim3(FS / 2, NB), dim3(FS, 2), 0, stream>>>(ctx, ws, out);
}

// Round 2
// 361.565 us; speedup vs baseline: 1.7196x; 1.7196x over previous
//
#include <hip/hip_runtime.h>
#include <math.h>

// Problem constants
#define CH   64     // C
#define FD   128    // F
#define HS   64     // half-res spatial
#define FS   128    // full-res spatial
#define NB   8      // B
#define NCTX 3      // N

// workspace layout (float offsets)
#define WS_WQ   0                              // Wq[C][F]
#define WS_BQ   (WS_WQ  + CH*FD)               // bq[C]
#define WS_QT   (WS_BQ  + CH)                  // qt  [B][C][HS][HS]
#define WS_VAL  (WS_QT  + NB*CH*HS*HS)         // val [B][C][HS][HS]
#define WS_L3   (WS_VAL + NB*CH*HS*HS)         // l3  [B][HS][HS]
#define WS_ATH  (WS_L3  + NB*HS*HS)            // AT hi bf16 [64][1152] (36864 floats)
#define WS_ATL  (WS_ATH + (CH*1152)/2)
#define WS_MTH  (WS_ATL + (CH*1152)/2)         // mT hi bf16 [B][66][66][128]
#define MT_ELEMS (NB*66*66*128)
#define WS_MTL  (WS_MTH + MT_ELEMS/2)
#define WS_END  (WS_MTL + MT_ELEMS/2)          // ~8.77M floats = 35.1 MB

typedef short  s16x8  __attribute__((ext_vector_type(8)));
typedef float  f32x16 __attribute__((ext_vector_type(16)));

__device__ inline unsigned short bf16_rne(float x) {
  unsigned u = __float_as_uint(x);
  u += 0x7FFFu + ((u >> 16) & 1u);
  return (unsigned short)(u >> 16);
}
__device__ inline void split2(float x, unsigned short& h, unsigned short& l) {
  h = bf16_rne(x);
  float hf = __uint_as_float((unsigned)h << 16);
  l = bf16_rne(x - hf);
}

// ---------------------------------------------------------------------------
// Kernel 1: Wq = Wc^T Wf ; bq = Wc^T bf  (bc*q cancels in softmax -> dropped)
// ---------------------------------------------------------------------------
__global__ __launch_bounds__(256) void prep_weights(
    const float* __restrict__ Wc, const float* __restrict__ Wf,
    const float* __restrict__ bf, float* __restrict__ ws) {
  int i = blockIdx.x * 256 + threadIdx.x;   // 0..8191
  int c = i >> 7, f = i & 127;
  float acc = 0.f;
#pragma unroll 8
  for (int d = 0; d < CH; ++d)
    acc = fmaf(Wc[d * CH + c], Wf[d * FD + f], acc);
  ws[WS_WQ + i] = acc;
  if (i < CH) {
    float b = 0.f;
#pragma unroll 8
    for (int d = 0; d < CH; ++d) b = fmaf(Wc[d * CH + i], bf[d], b);
    ws[WS_BQ + i] = b;
  }
}

// ---------------------------------------------------------------------------
// Kernel 1b: Vw[c][f][tap] -> AT[c][k=tap*128+f] split bf16 hi/lo
// ---------------------------------------------------------------------------
__global__ __launch_bounds__(256) void transform_w(
    const float* __restrict__ Vw, unsigned short* __restrict__ ath,
    unsigned short* __restrict__ atl) {
  int i = blockIdx.x * 256 + threadIdx.x;   // 0..73727
  if (i >= CH * 1152) return;
  int c = i / 1152;
  int r = i - c * 1152;            // k = tap*128 + f
  int tap = r >> 7, f = r & 127;
  float v = Vw[(c * FD + f) * 9 + tap];
  unsigned short h, l; split2(v, h, l);
  ath[i] = h; atl[i] = l;
}

// ---------------------------------------------------------------------------
// Kernel 1c: m[b][f][y][x] -> mT[b][y+1][x+1][f] split bf16 hi/lo
// (borders of the 66x66 grid pre-zeroed by hipMemsetAsync)
// ---------------------------------------------------------------------------
__global__ __launch_bounds__(256) void transform_m(
    const float* __restrict__ m, unsigned short* __restrict__ mth,
    unsigned short* __restrict__ mtl) {
  const int b = blockIdx.x >> 6;
  const int y = blockIdx.x & 63;
  const int x = threadIdx.x & 63;
  const int fg = threadIdx.x >> 6;       // 0..3
  for (int f = fg; f < FD; f += 4) {
    float v = m[((b * FD + f) * HS + y) * HS + x];
    unsigned short h, l; split2(v, h, l);
    int o = ((b * 66 + y + 1) * 66 + (x + 1)) * FD + f;
    mth[o] = h; mtl[o] = l;
  }
}

// ---------------------------------------------------------------------------
// Kernel 2 (half-res): qt = Wq*m + bq ; keys = Wk*m + bk ; l3 = qt.keys
// Weights staged in LDS (broadcast reads) -- no scalar-load latency chain.
// ---------------------------------------------------------------------------
__global__ __launch_bounds__(256) void half_qt_kernel(
    const float* __restrict__ m, const float* __restrict__ Wk,
    const float* __restrict__ bk, float* __restrict__ ws) {
  __shared__ float sWq[CH * FD];
  __shared__ float sWk[CH * FD];
  __shared__ float red[4][64];
  const int t = threadIdx.x;
  for (int i = t; i < CH * FD; i += 256) {
    sWq[i] = ws[WS_WQ + i];
    sWk[i] = Wk[i];
  }
  __syncthreads();

  const int b = blockIdx.x >> 6;
  const int y = blockIdx.x & 63;
  const int x = t & 63;
  const int wave = t >> 6;
  const int c0 = wave * 16;

  float qa[16], ka[16];
#pragma unroll
  for (int j = 0; j < 16; ++j) { qa[j] = ws[WS_BQ + c0 + j]; ka[j] = bk[c0 + j]; }

  const float* mp = m + ((b * FD) * HS + y) * HS + x;
  for (int fc = 0; fc < FD; fc += 8) {
    float mv[8];
#pragma unroll
    for (int u = 0; u < 8; ++u) mv[u] = mp[(fc + u) * HS * HS];
#pragma unroll
    for (int j = 0; j < 16; ++j) {
      const float4* wq4 = (const float4*)&sWq[(c0 + j) * FD + fc];
      const float4* wk4 = (const float4*)&sWk[(c0 + j) * FD + fc];
      float4 q0 = wq4[0], q1 = wq4[1], k0 = wk4[0], k1 = wk4[1];
      qa[j] = fmaf(q0.x, mv[0], qa[j]); qa[j] = fmaf(q0.y, mv[1], qa[j]);
      qa[j] = fmaf(q0.z, mv[2], qa[j]); qa[j] = fmaf(q0.w, mv[3], qa[j]);
      qa[j] = fmaf(q1.x, mv[4], qa[j]); qa[j] = fmaf(q1.y, mv[5], qa[j]);
      qa[j] = fmaf(q1.z, mv[6], qa[j]); qa[j] = fmaf(q1.w, mv[7], qa[j]);
      ka[j] = fmaf(k0.x, mv[0], ka[j]); ka[j] = fmaf(k0.y, mv[1], ka[j]);
      ka[j] = fmaf(k0.z, mv[2], ka[j]); ka[j] = fmaf(k0.w, mv[3], ka[j]);
      ka[j] = fmaf(k1.x, mv[4], ka[j]); ka[j] = fmaf(k1.y, mv[5], ka[j]);
      ka[j] = fmaf(k1.z, mv[6], ka[j]); ka[j] = fmaf(k1.w, mv[7], ka[j]);
    }
  }

  float* qt = ws + WS_QT;
#pragma unroll
  for (int j = 0; j < 16; ++j)
    qt[((b * CH + c0 + j) * HS + y) * HS + x] = qa[j];

  float part = 0.f;
#pragma unroll
  for (int j = 0; j < 16; ++j) part = fmaf(qa[j], ka[j], part);
  red[wave][x] = part;
  __syncthreads();
  if (t < 64) {
    float l3 = red[0][x] + red[1][x] + red[2][x] + red[3][x];
    ws[WS_L3 + (b * HS + y) * HS + x] = l3;
  }
}

// ---------------------------------------------------------------------------
// Kernel 3: conv3x3 as implicit GEMM via bf16-split MFMA.
// val[64ch][pix] = AT[64][1152] x im2col[1152][pix];  (a_h+a_l)(b_h+b_l) ~ hh+hl+lh
// Wave tile: 32ch x 32px, mfma_f32_32x32x16_bf16, K = 9 taps * 128 f.
// ---------------------------------------------------------------------------
__global__ __launch_bounds__(256) void conv_mfma(
    const unsigned short* __restrict__ mth, const unsigned short* __restrict__ mtl,
    const unsigned short* __restrict__ ath, const unsigned short* __restrict__ atl,
    const float* __restrict__ Vb, float* __restrict__ ws) {
  const int b = blockIdx.x >> 6;
  const int y = blockIdx.x & 63;
  const int lane = threadIdx.x & 63;
  const int wave = __builtin_amdgcn_readfirstlane(threadIdx.x >> 6);
  const int ch0 = (wave >> 1) * 32;
  const int x0  = (wave & 1) * 32;
  const int am  = lane & 31;       // A row (channel) == B col (pixel) == C col
  const int kh  = lane >> 5;       // k-half: k = kh*8 + j within chunk of 16

  f32x16 acc_hh, acc_hl, acc_lh;
#pragma unroll
  for (int i = 0; i < 16; ++i) { acc_hh[i] = 0.f; acc_hl[i] = 0.f; acc_lh[i] = 0.f; }

  const unsigned short* arow_h = ath + (ch0 + am) * 1152 + kh * 8;
  const unsigned short* arow_l = atl + (ch0 + am) * 1152 + kh * 8;

  for (int tap = 0; tap < 9; ++tap) {
    const int dy = tap / 3 - 1, dx = tap % 3 - 1;
    const int boff = ((b * 66 + y + dy + 1) * 66 + (x0 + am + dx + 1)) * FD + kh * 8;
    const unsigned short* bh_p = mth + boff;
    const unsigned short* bl_p = mtl + boff;
    const unsigned short* ah_p = arow_h + tap * FD;
    const unsigned short* al_p = arow_l + tap * FD;
#pragma unroll
    for (int kf = 0; kf < 8; ++kf) {
      s16x8 ah = *(const s16x8*)(ah_p + kf * 16);
      s16x8 al = *(const s16x8*)(al_p + kf * 16);
      s16x8 bh = *(const s16x8*)(bh_p + kf * 16);
      s16x8 bl = *(const s16x8*)(bl_p + kf * 16);
      acc_hh = __builtin_amdgcn_mfma_f32_32x32x16_bf16(ah, bh, acc_hh, 0, 0, 0);
      acc_hl = __builtin_amdgcn_mfma_f32_32x32x16_bf16(ah, bl, acc_hl, 0, 0, 0);
      acc_lh = __builtin_amdgcn_mfma_f32_32x32x16_bf16(al, bh, acc_lh, 0, 0, 0);
    }
  }

  float* val = ws + WS_VAL;
  const int col = lane & 31;
#pragma unroll
  for (int reg = 0; reg < 16; ++reg) {
    int row = (reg & 3) + 8 * (reg >> 2) + 4 * kh;
    int c = ch0 + row;
    float v = acc_hh[reg] + acc_hl[reg] + acc_lh[reg] + Vb[c];
    val[((b * CH + c) * HS + y) * HS + (x0 + col)] = v;
  }
}

// ---------------------------------------------------------------------------
// Kernel 4 (full-res): logits -> softmax -> weighted sum (unchanged)
// ---------------------------------------------------------------------------
__global__ __launch_bounds__(256) void fullres_kernel(
    const float* __restrict__ ctx, const float* __restrict__ ws,
    float* __restrict__ out) {
  const int w = threadIdx.x;                        // 0..127
  const int hrow = blockIdx.x * 2 + threadIdx.y;    // 0..127
  const int b = blockIdx.y;
  const int h2 = hrow >> 1, w2 = w >> 1;

  const float* qt = ws + WS_QT + ((b * CH) * HS + h2) * HS + w2;
  const float* cb = ctx + (((size_t)b * NCTX * CH) * FS + hrow) * FS + w;
  const int cs = FS * FS;
  const int ns = CH * FS * FS;

  float l0 = 0.f, l1 = 0.f, l2 = 0.f;
#pragma unroll 4
  for (int c = 0; c < CH; ++c) {
    float q = qt[c * HS * HS];
    l0 = fmaf(cb[c * cs], q, l0);
    l1 = fmaf(cb[ns + c * cs], q, l1);
    l2 = fmaf(cb[2 * ns + c * cs], q, l2);
  }
  float l3 = ws[WS_L3 + (b * HS + h2) * HS + w2];

  float mx = fmaxf(fmaxf(l0, l1), fmaxf(l2, l3));
  float e0 = __expf(l0 - mx), e1 = __expf(l1 - mx);
  float e2 = __expf(l2 - mx), e3 = __expf(l3 - mx);
  float inv = 1.f / (e0 + e1 + e2 + e3);
  float a0 = e0 * inv, a1 = e1 * inv, a2 = e2 * inv, a3 = e3 * inv;

  const float* val = ws + WS_VAL + ((b * CH) * HS + h2) * HS + w2;
  float* op = out + ((size_t)(b * CH) * FS + hrow) * FS + w;
#pragma unroll 4
  for (int c = 0; c < CH; ++c) {
    float o = a3 * val[c * HS * HS];
    o = fmaf(a0, cb[c * cs], o);
    o = fmaf(a1, cb[ns + c * cs], o);
    o = fmaf(a2, cb[2 * ns + c * cs], o);
    op[c * cs] = o;
  }
}

// ---------------------------------------------------------------------------
extern "C" void kernel_launch(void* const* d_in, const int* in_sizes, int n_in,
                              void* d_out, int out_size, void* d_ws, size_t ws_size,
                              hipStream_t stream) {
  const float* ctx = (const float*)d_in[0];
  const float* ms  = (const float*)d_in[1];
  const float* Wc  = (const float*)d_in[2];
  // d_in[3] = bc : cancels in softmax
  const float* Wf  = (const float*)d_in[4];
  const float* bf  = (const float*)d_in[5];
  const float* Wk  = (const float*)d_in[6];
  const float* bk  = (const float*)d_in[7];
  const float* Vw  = (const float*)d_in[8];
  const float* Vb  = (const float*)d_in[9];
  float* ws  = (float*)d_ws;
  float* out = (float*)d_out;

  unsigned short* ath = (unsigned short*)(ws + WS_ATH);
  unsigned short* atl = (unsigned short*)(ws + WS_ATL);
  unsigned short* mth = (unsigned short*)(ws + WS_MTH);
  unsigned short* mtl = (unsigned short*)(ws + WS_MTL);

  // zero mT (borders must read as 0; interior overwritten by transform_m)
  hipMemsetAsync(ws + WS_MTH, 0, (size_t)MT_ELEMS * 2 * sizeof(unsigned short), stream);

  prep_weights<<<32, 256, 0, stream>>>(Wc, Wf, bf, ws);
  transform_w<<<(CH * 1152 + 255) / 256, 256, 0, stream>>>(Vw, ath, atl);
  transform_m<<<NB * HS, 256, 0, stream>>>(ms, mth, mtl);
  half_qt_kernel<<<NB * HS, 256, 0, stream>>>(ms, Wk, bk, ws);
  conv_mfma<<<NB * HS, 256, 0, stream>>>(mth, mtl, ath, atl, Vb, ws);
  fullres_kernel<<<dim3(FS / 2, NB), dim3(FS, 2), 0, stream>>>(ctx, ws, out);
}

// Round 3
// 292.178 us; speedup vs baseline: 2.1280x; 1.2375x over previous
//
#include <hip/hip_runtime.h>
#include <math.h>

// Problem constants
#define CH   64
#define FD   128
#define HS   64
#define FS   128
#define NB   8
#define NCTX 3

// workspace layout (float offsets)
#define WS_QT   0                       // qt  [B][64][64][64] fp32 (with bias)
#define WS_VAL  2097152                 // val [B][64][64][64] fp32
#define WS_L3   4194304                 // l3  [B][64][64]
#define WS_BQ   4227072                 // bq[64]
#define WS_AVH  4227136                 // val A frags hi: [2][72][64][8] shorts (36864 f)
#define WS_AVL  4264000
#define WS_AQH  4300864                 // qt A frags hi: [2][8][64][8] shorts (4096 f)
#define WS_AQL  4304960
#define WS_AKH  4309056                 // keys A frags
#define WS_AKL  4313152
#define WS_MTH  4317248                 // m bf16 hi [B][66][66][128] shorts (2230272 f)
#define WS_MTL  6547520
// END 8777792 floats = 35.1 MB

typedef short  s16x8  __attribute__((ext_vector_type(8)));
typedef float  f32x16 __attribute__((ext_vector_type(16)));

__device__ inline unsigned short bf16_rne(float x) {
  unsigned u = __float_as_uint(x);
  u += 0x7FFFu + ((u >> 16) & 1u);
  return (unsigned short)(u >> 16);
}
__device__ inline void split2(float x, unsigned short& h, unsigned short& l) {
  h = bf16_rne(x);
  l = bf16_rne(x - __uint_as_float((unsigned)h << 16));
}

// ---------------------------------------------------------------------------
// a_prep: build all MFMA A-operand fragments in lane-contiguous order, + bq.
// jobs: [0,9216) val frags; [9216,10240) qt frags (Wq computed inline);
//       [10240,11264) key frags; [11264,11328) bq.
// ---------------------------------------------------------------------------
__global__ __launch_bounds__(256) void a_prep(
    const float* __restrict__ Wc, const float* __restrict__ Wf,
    const float* __restrict__ bf, const float* __restrict__ Wk,
    const float* __restrict__ Vw, float* __restrict__ ws) {
  int id = blockIdx.x * 256 + threadIdx.x;
  unsigned short* avh = (unsigned short*)(ws + WS_AVH);
  unsigned short* avl = (unsigned short*)(ws + WS_AVL);
  unsigned short* aqh = (unsigned short*)(ws + WS_AQH);
  unsigned short* aql = (unsigned short*)(ws + WS_AQL);
  unsigned short* akh = (unsigned short*)(ws + WS_AKH);
  unsigned short* akl = (unsigned short*)(ws + WS_AKL);

  if (id < 9216) {                       // val: Vw[c][f][tap] -> frag order
    int tile = id / 4608, rem = id % 4608;
    int q = rem >> 6, l = rem & 63;
    int am = l & 31, kh = l >> 5;
    int c = tile * 32 + am, tap = q >> 3, kf = q & 7;
#pragma unroll
    for (int j = 0; j < 8; ++j) {
      int f = kf * 16 + kh * 8 + j;
      unsigned short h, lo;
      split2(Vw[(c * FD + f) * 9 + tap], h, lo);
      avh[id * 8 + j] = h; avl[id * 8 + j] = lo;
    }
  } else if (id < 10240) {               // qt: Wq = Wc^T Wf, inline
    int i2 = id - 9216;
    int tile = i2 >> 9, rem = i2 & 511;
    int q = rem >> 6, l = rem & 63;
    int am = l & 31, kh = l >> 5;
    int c = tile * 32 + am;
#pragma unroll
    for (int j = 0; j < 8; ++j) {
      int f = q * 16 + kh * 8 + j;
      float acc = 0.f;
      for (int d = 0; d < CH; ++d)
        acc = fmaf(Wc[d * CH + c], Wf[d * FD + f], acc);
      unsigned short h, lo; split2(acc, h, lo);
      aqh[i2 * 8 + j] = h; aql[i2 * 8 + j] = lo;
    }
  } else if (id < 11264) {               // keys: Wk direct
    int i3 = id - 10240;
    int tile = i3 >> 9, rem = i3 & 511;
    int q = rem >> 6, l = rem & 63;
    int am = l & 31, kh = l >> 5;
    int c = tile * 32 + am;
#pragma unroll
    for (int j = 0; j < 8; ++j) {
      int f = q * 16 + kh * 8 + j;
      unsigned short h, lo; split2(Wk[c * FD + f], h, lo);
      akh[i3 * 8 + j] = h; akl[i3 * 8 + j] = lo;
    }
  } else if (id < 11328) {               // bq = Wc^T bf
    int c = id - 11264;
    float acc = 0.f;
    for (int d = 0; d < CH; ++d) acc = fmaf(Wc[d * CH + c], bf[d], acc);
    ws[WS_BQ + c] = acc;
  }
}

// ---------------------------------------------------------------------------
// m_setup: m[b][f][y][x] -> mT[b][y+1][x+1][f] bf16 hi/lo, borders zeroed
// in-kernel (no memset). Coalesced 256B reads, 16B/lane writes.
// ---------------------------------------------------------------------------
__global__ __launch_bounds__(256) void m_setup(
    const float* __restrict__ m, unsigned short* __restrict__ mth,
    unsigned short* __restrict__ mtl) {
  const int b = blockIdx.x / 66, yp = blockIdx.x % 66;
  const int lane = threadIdx.x & 63;
  const int wave = threadIdx.x >> 6;
  const int yy = yp - 1;
  const bool rowok = (yy >= 0) && (yy < HS);
#pragma unroll
  for (int cc = 0; cc < 4; ++cc) {
    const int f0 = wave * 32 + cc * 8;
    float v[8];
    if (rowok) {
#pragma unroll
      for (int j = 0; j < 8; ++j)
        v[j] = m[((b * FD + f0 + j) * HS + yy) * HS + lane];
    } else {
#pragma unroll
      for (int j = 0; j < 8; ++j) v[j] = 0.f;
    }
    s16x8 hi, lo;
#pragma unroll
    for (int j = 0; j < 8; ++j) {
      unsigned short h, l; split2(v[j], h, l);
      hi[j] = (short)h; lo[j] = (short)l;
    }
    size_t base = ((size_t)(b * 66 + yp) * 66 + (lane + 1)) * FD + f0;
    *(s16x8*)(mth + base) = hi;
    *(s16x8*)(mtl + base) = lo;
    if (lane < 2) {                      // x' = 0 and 65 borders
      s16x8 z;
#pragma unroll
      for (int j = 0; j < 8; ++j) z[j] = 0;
      size_t bb = ((size_t)(b * 66 + yp) * 66 + lane * 65) * FD + f0;
      *(s16x8*)(mth + bb) = z;
      *(s16x8*)(mtl + bb) = z;
    }
  }
}

// ---------------------------------------------------------------------------
// main_mfma: per (b,y) block, 8 waves.
// Phase 1: val = conv3x3 (A hi/lo x B hi, 2 MFMA/chunk), K split over wave>>2,
//          LDS pair-reduce. Phase 2: waves 0-3 qt, 4-7 keys (3-MFMA split,
//          K=128 center tap), qt -> global+LDS, keys -> LDS. Then l3 = qt.keys.
// ---------------------------------------------------------------------------
__global__ __launch_bounds__(512) void main_mfma(
    const unsigned short* __restrict__ mth, const unsigned short* __restrict__ mtl,
    const float* __restrict__ Vb, const float* __restrict__ bk,
    float* __restrict__ ws) {
  const int b = blockIdx.x >> 6, y = blockIdx.x & 63;
  const int t = threadIdx.x, lane = t & 63;
  const int wave = __builtin_amdgcn_readfirstlane(t >> 6);
  const int am = lane & 31, kh = lane >> 5;
  const int w4 = wave & 3;
  const int x0 = (w4 & 1) * 32, ch0 = (w4 >> 1) * 32;
  const int ct = w4 >> 1;
  const int khalf = wave >> 2;

  const unsigned short* avh = (const unsigned short*)(ws + WS_AVH);
  const unsigned short* avl = (const unsigned short*)(ws + WS_AVL);

  __shared__ float red[4][16][64];
  __shared__ float qtb[2][64][32];
  __shared__ float keb[2][64][32];

  // ---- phase 1: val, chunks [khalf*36, khalf*36+36) ----
  f32x16 a1, a2;
#pragma unroll
  for (int i = 0; i < 16; ++i) { a1[i] = 0.f; a2[i] = 0.f; }
#pragma unroll 4
  for (int qi = 0; qi < 36; ++qi) {
    const int q = khalf * 36 + qi;
    const int tap = q >> 3, kf = q & 7;
    const s16x8 ah = *(const s16x8*)(avh + ((ct * 72 + q) * 64 + lane) * 8);
    const s16x8 al = *(const s16x8*)(avl + ((ct * 72 + q) * 64 + lane) * 8);
    const int row = y + tap / 3;             // y + dy + 1
    const int col = x0 + am + tap % 3;       // x + dx + 1
    const s16x8 bh = *(const s16x8*)(mth +
        ((size_t)(b * 66 + row) * 66 + col) * FD + kf * 16 + kh * 8);
    a1 = __builtin_amdgcn_mfma_f32_32x32x16_bf16(ah, bh, a1, 0, 0, 0);
    a2 = __builtin_amdgcn_mfma_f32_32x32x16_bf16(al, bh, a2, 0, 0, 0);
  }
  if (khalf) {
#pragma unroll
    for (int r = 0; r < 16; ++r) red[w4][r][lane] = a1[r] + a2[r];
  }
  __syncthreads();
  if (!khalf) {
#pragma unroll
    for (int r = 0; r < 16; ++r) {
      const int c = ch0 + (r & 3) + 8 * (r >> 2) + 4 * kh;
      float v = a1[r] + a2[r] + red[w4][r][lane] + Vb[c];
      ws[WS_VAL + ((b * CH + c) * HS + y) * HS + x0 + am] = v;
    }
  }

  // ---- phase 2: qt (waves 0-3) / keys (waves 4-7), K=128 center tap ----
  const unsigned short* Ah = (const unsigned short*)(ws + (khalf ? WS_AKH : WS_AQH));
  const unsigned short* Al = (const unsigned short*)(ws + (khalf ? WS_AKL : WS_AQL));
  f32x16 c1, c2;
#pragma unroll
  for (int i = 0; i < 16; ++i) { c1[i] = 0.f; c2[i] = 0.f; }
#pragma unroll
  for (int q = 0; q < 8; ++q) {
    const s16x8 ah = *(const s16x8*)(Ah + ((ct * 8 + q) * 64 + lane) * 8);
    const s16x8 al = *(const s16x8*)(Al + ((ct * 8 + q) * 64 + lane) * 8);
    const size_t base = ((size_t)(b * 66 + y + 1) * 66 + (x0 + am + 1)) * FD
                        + q * 16 + kh * 8;
    const s16x8 bh = *(const s16x8*)(mth + base);
    const s16x8 bl = *(const s16x8*)(mtl + base);
    c1 = __builtin_amdgcn_mfma_f32_32x32x16_bf16(ah, bh, c1, 0, 0, 0);
    c1 = __builtin_amdgcn_mfma_f32_32x32x16_bf16(al, bh, c1, 0, 0, 0);
    c2 = __builtin_amdgcn_mfma_f32_32x32x16_bf16(ah, bl, c2, 0, 0, 0);
  }
  const int ptile = w4 & 1;
#pragma unroll
  for (int r = 0; r < 16; ++r) {
    const int c = ch0 + (r & 3) + 8 * (r >> 2) + 4 * kh;
    if (khalf) {
      keb[ptile][c][am] = c1[r] + c2[r] + bk[c];
    } else {
      float v = c1[r] + c2[r] + ws[WS_BQ + c];
      qtb[ptile][c][am] = v;
      ws[WS_QT + ((b * CH + c) * HS + y) * HS + x0 + am] = v;
    }
  }
  __syncthreads();

  // ---- l3 = sum_c qt[c]*keys[c], waves 0,1 (one per px-tile) ----
  if (wave < 2) {
    float s = 0.f;
#pragma unroll 8
    for (int j = 0; j < 32; ++j)
      s = fmaf(qtb[wave][kh * 32 + j][am], keb[wave][kh * 32 + j][am], s);
    s += __shfl_xor(s, 32, 64);
    if (kh == 0)
      ws[WS_L3 + (b * HS + y) * HS + wave * 32 + am] = s;
  }
}

// ---------------------------------------------------------------------------
// fullres: 2048 blocks x 256 thr. Block = (b, hrow, xhalf); thread = (px, cg).
// pass1: partial logits over 16 ch, LDS reduce; softmax; pass2: output 16 ch.
// ---------------------------------------------------------------------------
__global__ __launch_bounds__(256) void fullres_kernel(
    const float* __restrict__ ctx, const float* __restrict__ ws,
    float* __restrict__ out) {
  const int xh = blockIdx.x & 1, hrow = blockIdx.x >> 1;
  const int b = blockIdx.y;
  const int px = threadIdx.x & 63, cg = threadIdx.x >> 6;
  const int x = xh * 64 + px;
  const int h2 = hrow >> 1, w2 = x >> 1;

  const float* qtp = ws + WS_QT + (size_t)(b * CH) * HS * HS + h2 * HS + w2;
  const float* cb  = ctx + (size_t)(b * NCTX * CH) * FS * FS + hrow * FS + x;
  const int cs = FS * FS, ns = CH * FS * FS;

  float l0 = 0.f, l1 = 0.f, l2 = 0.f;
#pragma unroll
  for (int j = 0; j < 16; ++j) {
    const int c = cg * 16 + j;
    const float q = qtp[c * HS * HS];
    l0 = fmaf(cb[c * cs], q, l0);
    l1 = fmaf(cb[ns + c * cs], q, l1);
    l2 = fmaf(cb[2 * ns + c * cs], q, l2);
  }
  __shared__ float red[3][4][64];
  red[0][cg][px] = l0; red[1][cg][px] = l1; red[2][cg][px] = l2;
  __syncthreads();
  float L0 = red[0][0][px] + red[0][1][px] + red[0][2][px] + red[0][3][px];
  float L1 = red[1][0][px] + red[1][1][px] + red[1][2][px] + red[1][3][px];
  float L2 = red[2][0][px] + red[2][1][px] + red[2][2][px] + red[2][3][px];
  float L3 = ws[WS_L3 + (b * HS + h2) * HS + w2];

  float mx = fmaxf(fmaxf(L0, L1), fmaxf(L2, L3));
  float e0 = __expf(L0 - mx), e1 = __expf(L1 - mx);
  float e2 = __expf(L2 - mx), e3 = __expf(L3 - mx);
  float inv = 1.f / (e0 + e1 + e2 + e3);
  float a0 = e0 * inv, a1 = e1 * inv, a2 = e2 * inv, a3 = e3 * inv;

  const float* valp = ws + WS_VAL + (size_t)(b * CH) * HS * HS + h2 * HS + w2;
  float* op = out + (size_t)(b * CH) * FS * FS + hrow * FS + x;
#pragma unroll
  for (int j = 0; j < 16; ++j) {
    const int c = cg * 16 + j;
    float o = a3 * valp[c * HS * HS];
    o = fmaf(a0, cb[c * cs], o);
    o = fmaf(a1, cb[ns + c * cs], o);
    o = fmaf(a2, cb[2 * ns + c * cs], o);
    op[c * cs] = o;
  }
}

// ---------------------------------------------------------------------------
extern "C" void kernel_launch(void* const* d_in, const int* in_sizes, int n_in,
                              void* d_out, int out_size, void* d_ws, size_t ws_size,
                              hipStream_t stream) {
  const float* ctx = (const float*)d_in[0];
  const float* ms  = (const float*)d_in[1];
  const float* Wc  = (const float*)d_in[2];
  // d_in[3] = bc : cancels in softmax
  const float* Wf  = (const float*)d_in[4];
  const float* bf  = (const float*)d_in[5];
  const float* Wk  = (const float*)d_in[6];
  const float* bk  = (const float*)d_in[7];
  const float* Vw  = (const float*)d_in[8];
  const float* Vb  = (const float*)d_in[9];
  float* ws  = (float*)d_ws;
  float* out = (float*)d_out;

  unsigned short* mth = (unsigned short*)(ws + WS_MTH);
  unsigned short* mtl = (unsigned short*)(ws + WS_MTL);

  a_prep<<<45, 256, 0, stream>>>(Wc, Wf, bf, Wk, Vw, ws);
  m_setup<<<NB * 66, 256, 0, stream>>>(ms, mth, mtl);
  main_mfma<<<NB * HS, 512, 0, stream>>>(mth, mtl, Vb, bk, ws);
  fullres_kernel<<<dim3(2 * FS, NB), 256, 0, stream>>>(ctx, ws, out);
}

// Round 4
// 271.343 us; speedup vs baseline: 2.2914x; 1.0768x over previous
//
#include <hip/hip_runtime.h>
#include <math.h>

// Problem constants
#define CH   64
#define FD   128
#define HS   64
#define FS   128
#define NB   8
#define NCTX 3

// workspace layout (float offsets)
#define WS_QT   0                       // qt  [B][64][64][64] fp32 (with bias)
#define WS_VAL  2097152                 // val [B][64][64][64] fp32
#define WS_L3   4194304                 // l3  [B][64][64]
#define WS_BQ   4227072                 // bq[64]
#define WS_AVH  4227136                 // val A frags hi: [2][72][64][8] shorts
#define WS_AVL  4264000
#define WS_AQH  4300864                 // qt A frags
#define WS_AQL  4304960
#define WS_AKH  4309056                 // key A frags
#define WS_AKL  4313152
#define WS_MTH  4317248                 // mT2 hi [B][66][8][66][2][8] shorts
#define WS_MTL  6547520                 // mT2 lo
// END 8777792 floats = 35.1 MB

// mT2: k-chunk-major so a wave's B-fragment (lanes = (col,kh)) is 1KB contiguous
#define MT2_IDX(b,row,kf,col,kh) \
  ((((((size_t)(b)*66+(row))*8+(kf))*66+(col))*2+(kh))*8)

typedef short  s16x8  __attribute__((ext_vector_type(8)));
typedef float  f32x16 __attribute__((ext_vector_type(16)));

__device__ inline unsigned short bf16_rne(float x) {
  unsigned u = __float_as_uint(x);
  u += 0x7FFFu + ((u >> 16) & 1u);
  return (unsigned short)(u >> 16);
}
__device__ inline void split2(float x, unsigned short& h, unsigned short& l) {
  h = bf16_rne(x);
  l = bf16_rne(x - __uint_as_float((unsigned)h << 16));
}

// ---------------------------------------------------------------------------
// setup_all: blocks [0,45) build A-fragments + bq; blocks [45,573) transform m.
// ---------------------------------------------------------------------------
__global__ __launch_bounds__(256) void setup_all(
    const float* __restrict__ Wc, const float* __restrict__ Wf,
    const float* __restrict__ bf, const float* __restrict__ Wk,
    const float* __restrict__ Vw, const float* __restrict__ m,
    float* __restrict__ ws) {
  if (blockIdx.x < 45) {
    // ---- A-fragment prep ----
    int id = blockIdx.x * 256 + threadIdx.x;
    unsigned short* avh = (unsigned short*)(ws + WS_AVH);
    unsigned short* avl = (unsigned short*)(ws + WS_AVL);
    unsigned short* aqh = (unsigned short*)(ws + WS_AQH);
    unsigned short* aql = (unsigned short*)(ws + WS_AQL);
    unsigned short* akh = (unsigned short*)(ws + WS_AKH);
    unsigned short* akl = (unsigned short*)(ws + WS_AKL);

    if (id < 9216) {                       // val: Vw[c][f][tap] -> frag order
      int tile = id / 4608, rem = id % 4608;
      int q = rem >> 6, l = rem & 63;
      int am = l & 31, kh = l >> 5;
      int c = tile * 32 + am, tap = q >> 3, kf = q & 7;
#pragma unroll
      for (int j = 0; j < 8; ++j) {
        int f = kf * 16 + kh * 8 + j;
        unsigned short h, lo;
        split2(Vw[(c * FD + f) * 9 + tap], h, lo);
        avh[id * 8 + j] = h; avl[id * 8 + j] = lo;
      }
    } else if (id < 10240) {               // qt: Wq = Wc^T Wf inline
      int i2 = id - 9216;
      int tile = i2 >> 9, rem = i2 & 511;
      int q = rem >> 6, l = rem & 63;
      int am = l & 31, kh = l >> 5;
      int c = tile * 32 + am;
#pragma unroll
      for (int j = 0; j < 8; ++j) {
        int f = q * 16 + kh * 8 + j;
        float acc = 0.f;
        for (int d = 0; d < CH; ++d)
          acc = fmaf(Wc[d * CH + c], Wf[d * FD + f], acc);
        unsigned short h, lo; split2(acc, h, lo);
        aqh[i2 * 8 + j] = h; aql[i2 * 8 + j] = lo;
      }
    } else if (id < 11264) {               // keys: Wk direct
      int i3 = id - 10240;
      int tile = i3 >> 9, rem = i3 & 511;
      int q = rem >> 6, l = rem & 63;
      int am = l & 31, kh = l >> 5;
      int c = tile * 32 + am;
#pragma unroll
      for (int j = 0; j < 8; ++j) {
        int f = q * 16 + kh * 8 + j;
        unsigned short h, lo; split2(Wk[c * FD + f], h, lo);
        akh[i3 * 8 + j] = h; akl[i3 * 8 + j] = lo;
      }
    } else if (id < 11328) {               // bq = Wc^T bf
      int c = id - 11264;
      float acc = 0.f;
      for (int d = 0; d < CH; ++d) acc = fmaf(Wc[d * CH + c], bf[d], acc);
      ws[WS_BQ + c] = acc;
    }
  } else {
    // ---- m transform: m[b][f][y][x] -> mT2 (k-chunk-major), borders zeroed
    unsigned short* mth = (unsigned short*)(ws + WS_MTH);
    unsigned short* mtl = (unsigned short*)(ws + WS_MTL);
    const int bid = blockIdx.x - 45;
    const int b = bid / 66, yp = bid % 66;
    const int lane = threadIdx.x & 63;
    const int wave = threadIdx.x >> 6;
    const int yy = yp - 1;
    const bool rowok = (yy >= 0) && (yy < HS);
#pragma unroll
    for (int cc = 0; cc < 4; ++cc) {
      const int f0 = wave * 32 + cc * 8;
      const int kf = f0 >> 4, kh = (f0 >> 3) & 1;
      float v[8];
      if (rowok) {
#pragma unroll
        for (int j = 0; j < 8; ++j)
          v[j] = m[((b * FD + f0 + j) * HS + yy) * HS + lane];
      } else {
#pragma unroll
        for (int j = 0; j < 8; ++j) v[j] = 0.f;
      }
      s16x8 hi, lo;
#pragma unroll
      for (int j = 0; j < 8; ++j) {
        unsigned short h, l; split2(v[j], h, l);
        hi[j] = (short)h; lo[j] = (short)l;
      }
      size_t base = MT2_IDX(b, yp, kf, lane + 1, kh);
      *(s16x8*)(mth + base) = hi;
      *(s16x8*)(mtl + base) = lo;
      if (lane < 2) {
        s16x8 z;
#pragma unroll
        for (int j = 0; j < 8; ++j) z[j] = 0;
        size_t bb = MT2_IDX(b, yp, kf, lane * 65, kh);
        *(s16x8*)(mth + bb) = z;
        *(s16x8*)(mtl + bb) = z;
      }
    }
  }
}

// ---------------------------------------------------------------------------
// main_mfma: per (b,y) block, 8 waves. Phase 1: conv val (K-split over waves,
// LDS pair-reduce). Phase 2: qt / keys GEMMs + l3 dot. All B-loads 1KB
// contiguous per wave thanks to mT2 layout.
// ---------------------------------------------------------------------------
__global__ __launch_bounds__(512) void main_mfma(
    const unsigned short* __restrict__ mth, const unsigned short* __restrict__ mtl,
    const float* __restrict__ Vb, const float* __restrict__ bk,
    float* __restrict__ ws) {
  const int b = blockIdx.x >> 6, y = blockIdx.x & 63;
  const int t = threadIdx.x, lane = t & 63;
  const int wave = __builtin_amdgcn_readfirstlane(t >> 6);
  const int am = lane & 31, kh = lane >> 5;
  const int w4 = wave & 3;
  const int x0 = (w4 & 1) * 32, ch0 = (w4 >> 1) * 32;
  const int ct = w4 >> 1;
  const int khalf = wave >> 2;

  const unsigned short* avh = (const unsigned short*)(ws + WS_AVH);
  const unsigned short* avl = (const unsigned short*)(ws + WS_AVL);

  __shared__ float red[4][16][64];
  __shared__ float qtb[2][64][32];
  __shared__ float keb[2][64][32];

  // ---- phase 1: val, chunks [khalf*36, khalf*36+36) ----
  f32x16 a1, a2;
#pragma unroll
  for (int i = 0; i < 16; ++i) { a1[i] = 0.f; a2[i] = 0.f; }
#pragma unroll 4
  for (int qi = 0; qi < 36; ++qi) {
    const int q = khalf * 36 + qi;
    const int tap = q >> 3, kf = q & 7;
    const s16x8 ah = *(const s16x8*)(avh + ((ct * 72 + q) * 64 + lane) * 8);
    const s16x8 al = *(const s16x8*)(avl + ((ct * 72 + q) * 64 + lane) * 8);
    const s16x8 bh = *(const s16x8*)(mth +
        MT2_IDX(b, y + tap / 3, kf, x0 + am + tap % 3, kh));
    a1 = __builtin_amdgcn_mfma_f32_32x32x16_bf16(ah, bh, a1, 0, 0, 0);
    a2 = __builtin_amdgcn_mfma_f32_32x32x16_bf16(al, bh, a2, 0, 0, 0);
  }
  if (khalf) {
#pragma unroll
    for (int r = 0; r < 16; ++r) red[w4][r][lane] = a1[r] + a2[r];
  }
  __syncthreads();
  if (!khalf) {
#pragma unroll
    for (int r = 0; r < 16; ++r) {
      const int c = ch0 + (r & 3) + 8 * (r >> 2) + 4 * kh;
      float v = a1[r] + a2[r] + red[w4][r][lane] + Vb[c];
      ws[WS_VAL + ((b * CH + c) * HS + y) * HS + x0 + am] = v;
    }
  }

  // ---- phase 2: qt (waves 0-3) / keys (waves 4-7), K=128 center tap ----
  const unsigned short* Ah = (const unsigned short*)(ws + (khalf ? WS_AKH : WS_AQH));
  const unsigned short* Al = (const unsigned short*)(ws + (khalf ? WS_AKL : WS_AQL));
  f32x16 c1, c2;
#pragma unroll
  for (int i = 0; i < 16; ++i) { c1[i] = 0.f; c2[i] = 0.f; }
#pragma unroll
  for (int q = 0; q < 8; ++q) {
    const s16x8 ah = *(const s16x8*)(Ah + ((ct * 8 + q) * 64 + lane) * 8);
    const s16x8 al = *(const s16x8*)(Al + ((ct * 8 + q) * 64 + lane) * 8);
    const size_t base = MT2_IDX(b, y + 1, q, x0 + am + 1, kh);
    const s16x8 bh = *(const s16x8*)(mth + base);
    const s16x8 bl = *(const s16x8*)(mtl + base);
    c1 = __builtin_amdgcn_mfma_f32_32x32x16_bf16(ah, bh, c1, 0, 0, 0);
    c1 = __builtin_amdgcn_mfma_f32_32x32x16_bf16(al, bh, c1, 0, 0, 0);
    c2 = __builtin_amdgcn_mfma_f32_32x32x16_bf16(ah, bl, c2, 0, 0, 0);
  }
  const int ptile = w4 & 1;
#pragma unroll
  for (int r = 0; r < 16; ++r) {
    const int c = ch0 + (r & 3) + 8 * (r >> 2) + 4 * kh;
    if (khalf) {
      keb[ptile][c][am] = c1[r] + c2[r] + bk[c];
    } else {
      float v = c1[r] + c2[r] + ws[WS_BQ + c];
      qtb[ptile][c][am] = v;
      ws[WS_QT + ((b * CH + c) * HS + y) * HS + x0 + am] = v;
    }
  }
  __syncthreads();

  // ---- l3 = sum_c qt[c]*keys[c], waves 0,1 ----
  if (wave < 2) {
    float s = 0.f;
#pragma unroll 8
    for (int j = 0; j < 32; ++j)
      s = fmaf(qtb[wave][kh * 32 + j][am], keb[wave][kh * 32 + j][am], s);
    s += __shfl_xor(s, 32, 64);
    if (kh == 0)
      ws[WS_L3 + (b * HS + y) * HS + wave * 32 + am] = s;
  }
}

// ---------------------------------------------------------------------------
// fullres: single HBM pass over ctx — each thread's pass-2 channels equal its
// pass-1 channels, so ctx values stay in registers across the softmax.
// ---------------------------------------------------------------------------
__global__ __launch_bounds__(256) void fullres_kernel(
    const float* __restrict__ ctx, const float* __restrict__ ws,
    float* __restrict__ out) {
  const int xh = blockIdx.x & 1, hrow = blockIdx.x >> 1;
  const int b = blockIdx.y;
  const int px = threadIdx.x & 63, cg = threadIdx.x >> 6;
  const int x = xh * 64 + px;
  const int h2 = hrow >> 1, w2 = x >> 1;

  const float* qtp = ws + WS_QT + (size_t)(b * CH) * HS * HS + h2 * HS + w2;
  const float* cb  = ctx + (size_t)(b * NCTX * CH) * FS * FS + hrow * FS + x;
  const int cs = FS * FS, ns = CH * FS * FS;

  float cv0[16], cv1[16], cv2[16];
  float l0 = 0.f, l1 = 0.f, l2 = 0.f;
#pragma unroll
  for (int j = 0; j < 16; ++j) {
    const int c = cg * 16 + j;
    cv0[j] = cb[c * cs];
    cv1[j] = cb[ns + c * cs];
    cv2[j] = cb[2 * ns + c * cs];
    const float q = qtp[c * HS * HS];
    l0 = fmaf(cv0[j], q, l0);
    l1 = fmaf(cv1[j], q, l1);
    l2 = fmaf(cv2[j], q, l2);
  }
  __shared__ float red[3][4][64];
  red[0][cg][px] = l0; red[1][cg][px] = l1; red[2][cg][px] = l2;
  __syncthreads();
  float L0 = red[0][0][px] + red[0][1][px] + red[0][2][px] + red[0][3][px];
  float L1 = red[1][0][px] + red[1][1][px] + red[1][2][px] + red[1][3][px];
  float L2 = red[2][0][px] + red[2][1][px] + red[2][2][px] + red[2][3][px];
  float L3 = ws[WS_L3 + (b * HS + h2) * HS + w2];

  float mx = fmaxf(fmaxf(L0, L1), fmaxf(L2, L3));
  float e0 = __expf(L0 - mx), e1 = __expf(L1 - mx);
  float e2 = __expf(L2 - mx), e3 = __expf(L3 - mx);
  float inv = 1.f / (e0 + e1 + e2 + e3);
  float a0 = e0 * inv, a1 = e1 * inv, a2 = e2 * inv, a3 = e3 * inv;

  const float* valp = ws + WS_VAL + (size_t)(b * CH) * HS * HS + h2 * HS + w2;
  float* op = out + (size_t)(b * CH) * FS * FS + hrow * FS + x;
#pragma unroll
  for (int j = 0; j < 16; ++j) {
    const int c = cg * 16 + j;
    float o = a3 * valp[c * HS * HS];
    o = fmaf(a0, cv0[j], o);
    o = fmaf(a1, cv1[j], o);
    o = fmaf(a2, cv2[j], o);
    op[c * cs] = o;
  }
}

// ---------------------------------------------------------------------------
extern "C" void kernel_launch(void* const* d_in, const int* in_sizes, int n_in,
                              void* d_out, int out_size, void* d_ws, size_t ws_size,
                              hipStream_t stream) {
  const float* ctx = (const float*)d_in[0];
  const float* ms  = (const float*)d_in[1];
  const float* Wc  = (const float*)d_in[2];
  // d_in[3] = bc : cancels in softmax
  const float* Wf  = (const float*)d_in[4];
  const float* bf  = (const float*)d_in[5];
  const float* Wk  = (const float*)d_in[6];
  const float* bk  = (const float*)d_in[7];
  const float* Vw  = (const float*)d_in[8];
  const float* Vb  = (const float*)d_in[9];
  float* ws  = (float*)d_ws;
  float* out = (float*)d_out;

  unsigned short* mth = (unsigned short*)(ws + WS_MTH);
  unsigned short* mtl = (unsigned short*)(ws + WS_MTL);

  setup_all<<<45 + NB * 66, 256, 0, stream>>>(Wc, Wf, bf, Wk, Vw, ms, ws);
  main_mfma<<<NB * HS, 512, 0, stream>>>(mth, mtl, Vb, bk, ws);
  fullres_kernel<<<dim3(2 * FS, NB), 256, 0, stream>>>(ctx, ws, out);
}

// Round 5
// 252.858 us; speedup vs baseline: 2.4589x; 1.0731x over previous
//
#include <hip/hip_runtime.h>
#include <math.h>

// Problem constants
#define CH   64
#define FD   128
#define HS   64
#define FS   128
#define NB   8
#define NCTX 3

// workspace layout (float offsets)
#define WS_QT   0                       // qt  [B][64][64][64] fp32 (with bias)
#define WS_VAL  2097152                 // val [B][64][64][64] fp32
#define WS_L3   4194304                 // l3  [B][64][64]
#define WS_BQ   4227072                 // bq[64]
#define WS_AVH  4227136                 // val A frags hi: [2][72][64][8] shorts
#define WS_AVL  4264000                 // (unused this round)
#define WS_AQH  4300864                 // qt A frags
#define WS_AQL  4304960
#define WS_AKH  4309056                 // key A frags
#define WS_AKL  4313152
#define WS_MTH  4317248                 // mT2 hi [B][66][8][66][2][8] shorts
#define WS_MTL  6547520                 // mT2 lo
// END 8777792 floats = 35.1 MB

// mT2: k-chunk-major so a wave's B-fragment (lanes = (col,kh)) is 1KB contiguous
#define MT2_IDX(b,row,kf,col,kh) \
  ((((((size_t)(b)*66+(row))*8+(kf))*66+(col))*2+(kh))*8)

typedef short  s16x8  __attribute__((ext_vector_type(8)));
typedef float  f32x16 __attribute__((ext_vector_type(16)));

__device__ inline unsigned short bf16_rne(float x) {
  unsigned u = __float_as_uint(x);
  u += 0x7FFFu + ((u >> 16) & 1u);
  return (unsigned short)(u >> 16);
}
__device__ inline void split2(float x, unsigned short& h, unsigned short& l) {
  h = bf16_rne(x);
  l = bf16_rne(x - __uint_as_float((unsigned)h << 16));
}

// ---------------------------------------------------------------------------
// setup_all: blocks [0,45) build A-fragments + bq; blocks [45,573) transform m.
// ---------------------------------------------------------------------------
__global__ __launch_bounds__(256) void setup_all(
    const float* __restrict__ Wc, const float* __restrict__ Wf,
    const float* __restrict__ bf, const float* __restrict__ Wk,
    const float* __restrict__ Vw, const float* __restrict__ m,
    float* __restrict__ ws) {
  if (blockIdx.x < 45) {
    int id = blockIdx.x * 256 + threadIdx.x;
    unsigned short* avh = (unsigned short*)(ws + WS_AVH);
    unsigned short* aqh = (unsigned short*)(ws + WS_AQH);
    unsigned short* aql = (unsigned short*)(ws + WS_AQL);
    unsigned short* akh = (unsigned short*)(ws + WS_AKH);
    unsigned short* akl = (unsigned short*)(ws + WS_AKL);

    if (id < 9216) {                       // val frags: hi only
      int tile = id / 4608, rem = id % 4608;
      int q = rem >> 6, l = rem & 63;
      int am = l & 31, kh = l >> 5;
      int c = tile * 32 + am, tap = q >> 3, kf = q & 7;
#pragma unroll
      for (int j = 0; j < 8; ++j) {
        int f = kf * 16 + kh * 8 + j;
        avh[id * 8 + j] = bf16_rne(Vw[(c * FD + f) * 9 + tap]);
      }
    } else if (id < 10240) {               // qt: Wq = Wc^T Wf inline
      int i2 = id - 9216;
      int tile = i2 >> 9, rem = i2 & 511;
      int q = rem >> 6, l = rem & 63;
      int am = l & 31, kh = l >> 5;
      int c = tile * 32 + am;
#pragma unroll
      for (int j = 0; j < 8; ++j) {
        int f = q * 16 + kh * 8 + j;
        float acc = 0.f;
        for (int d = 0; d < CH; ++d)
          acc = fmaf(Wc[d * CH + c], Wf[d * FD + f], acc);
        unsigned short h, lo; split2(acc, h, lo);
        aqh[i2 * 8 + j] = h; aql[i2 * 8 + j] = lo;
      }
    } else if (id < 11264) {               // keys: Wk direct
      int i3 = id - 10240;
      int tile = i3 >> 9, rem = i3 & 511;
      int q = rem >> 6, l = rem & 63;
      int am = l & 31, kh = l >> 5;
      int c = tile * 32 + am;
#pragma unroll
      for (int j = 0; j < 8; ++j) {
        int f = q * 16 + kh * 8 + j;
        unsigned short h, lo; split2(Wk[c * FD + f], h, lo);
        akh[i3 * 8 + j] = h; akl[i3 * 8 + j] = lo;
      }
    } else if (id < 11328) {               // bq = Wc^T bf
      int c = id - 11264;
      float acc = 0.f;
      for (int d = 0; d < CH; ++d) acc = fmaf(Wc[d * CH + c], bf[d], acc);
      ws[WS_BQ + c] = acc;
    }
  } else {
    unsigned short* mth = (unsigned short*)(ws + WS_MTH);
    unsigned short* mtl = (unsigned short*)(ws + WS_MTL);
    const int bid = blockIdx.x - 45;
    const int b = bid / 66, yp = bid % 66;
    const int lane = threadIdx.x & 63;
    const int wave = threadIdx.x >> 6;
    const int yy = yp - 1;
    const bool rowok = (yy >= 0) && (yy < HS);
#pragma unroll
    for (int cc = 0; cc < 4; ++cc) {
      const int f0 = wave * 32 + cc * 8;
      const int kf = f0 >> 4, kh = (f0 >> 3) & 1;
      float v[8];
      if (rowok) {
#pragma unroll
        for (int j = 0; j < 8; ++j)
          v[j] = m[((b * FD + f0 + j) * HS + yy) * HS + lane];
      } else {
#pragma unroll
        for (int j = 0; j < 8; ++j) v[j] = 0.f;
      }
      s16x8 hi, lo;
#pragma unroll
      for (int j = 0; j < 8; ++j) {
        unsigned short h, l; split2(v[j], h, l);
        hi[j] = (short)h; lo[j] = (short)l;
      }
      size_t base = MT2_IDX(b, yp, kf, lane + 1, kh);
      *(s16x8*)(mth + base) = hi;
      *(s16x8*)(mtl + base) = lo;
      if (lane < 2) {
        s16x8 z;
#pragma unroll
        for (int j = 0; j < 8; ++j) z[j] = 0;
        size_t bb = MT2_IDX(b, yp, kf, lane * 65, kh);
        *(s16x8*)(mth + bb) = z;
        *(s16x8*)(mtl + bb) = z;
      }
    }
  }
}

// ---------------------------------------------------------------------------
// main_mfma: per (b,y) block, 16 waves (1024 thr).
// Phase 1: conv val, A-hi only (1 MFMA + 2 loads/chunk), K split 4-way over
// khalf=wave>>2, LDS reduce. Phase 2: waves 0-7 qt/keys GEMMs. Then l3.
// ---------------------------------------------------------------------------
__global__ __launch_bounds__(1024, 8) void main_mfma(
    const unsigned short* __restrict__ mth, const unsigned short* __restrict__ mtl,
    const float* __restrict__ Vb, const float* __restrict__ bk,
    float* __restrict__ ws) {
  const int b = blockIdx.x >> 6, y = blockIdx.x & 63;
  const int t = threadIdx.x, lane = t & 63;
  const int wave = __builtin_amdgcn_readfirstlane(t >> 6);
  const int am = lane & 31, kh = lane >> 5;
  const int tile = wave & 3;
  const int x0 = (tile & 1) * 32, ch0 = (tile >> 1) * 32;
  const int ct = tile >> 1;
  const int khalf = wave >> 2;            // 0..3

  const unsigned short* avh = (const unsigned short*)(ws + WS_AVH);

  __shared__ float red[3][4][16][64];     // 48 KB
  __shared__ float qtb[2][64][32];        // 8 KB
  __shared__ float keb[2][64][32];        // 8 KB

  // ---- phase 1: val, chunks [khalf*18, khalf*18+18), A-hi only ----
  f32x16 a1;
#pragma unroll
  for (int i = 0; i < 16; ++i) a1[i] = 0.f;
#pragma unroll 6
  for (int qi = 0; qi < 18; ++qi) {
    const int q = khalf * 18 + qi;
    const int tap = q >> 3, kf = q & 7;
    const s16x8 ah = *(const s16x8*)(avh + ((ct * 72 + q) * 64 + lane) * 8);
    const s16x8 bh = *(const s16x8*)(mth +
        MT2_IDX(b, y + tap / 3, kf, x0 + am + tap % 3, kh));
    a1 = __builtin_amdgcn_mfma_f32_32x32x16_bf16(ah, bh, a1, 0, 0, 0);
  }
  if (khalf) {
#pragma unroll
    for (int r = 0; r < 16; ++r) red[khalf - 1][tile][r][lane] = a1[r];
  }
  __syncthreads();
  if (!khalf) {
#pragma unroll
    for (int r = 0; r < 16; ++r) {
      const int c = ch0 + (r & 3) + 8 * (r >> 2) + 4 * kh;
      float v = a1[r] + red[0][tile][r][lane] + red[1][tile][r][lane]
              + red[2][tile][r][lane] + Vb[c];
      ws[WS_VAL + ((b * CH + c) * HS + y) * HS + x0 + am] = v;
    }
  }

  // ---- phase 2: waves 0-3 qt, waves 4-7 keys (K=128 center tap, 3-MFMA) ----
  if (khalf < 2) {
    const unsigned short* Ah = (const unsigned short*)(ws + (khalf ? WS_AKH : WS_AQH));
    const unsigned short* Al = (const unsigned short*)(ws + (khalf ? WS_AKL : WS_AQL));
    f32x16 c1, c2;
#pragma unroll
    for (int i = 0; i < 16; ++i) { c1[i] = 0.f; c2[i] = 0.f; }
#pragma unroll
    for (int q = 0; q < 8; ++q) {
      const s16x8 ah = *(const s16x8*)(Ah + ((ct * 8 + q) * 64 + lane) * 8);
      const s16x8 al = *(const s16x8*)(Al + ((ct * 8 + q) * 64 + lane) * 8);
      const size_t base = MT2_IDX(b, y + 1, q, x0 + am + 1, kh);
      const s16x8 bh = *(const s16x8*)(mth + base);
      const s16x8 bl = *(const s16x8*)(mtl + base);
      c1 = __builtin_amdgcn_mfma_f32_32x32x16_bf16(ah, bh, c1, 0, 0, 0);
      c1 = __builtin_amdgcn_mfma_f32_32x32x16_bf16(al, bh, c1, 0, 0, 0);
      c2 = __builtin_amdgcn_mfma_f32_32x32x16_bf16(ah, bl, c2, 0, 0, 0);
    }
    const int ptile = tile & 1;
#pragma unroll
    for (int r = 0; r < 16; ++r) {
      const int c = ch0 + (r & 3) + 8 * (r >> 2) + 4 * kh;
      if (khalf) {
        keb[ptile][c][am] = c1[r] + c2[r] + bk[c];
      } else {
        float v = c1[r] + c2[r] + ws[WS_BQ + c];
        qtb[ptile][c][am] = v;
        ws[WS_QT + ((b * CH + c) * HS + y) * HS + x0 + am] = v;
      }
    }
  }
  __syncthreads();

  // ---- l3 = sum_c qt[c]*keys[c], waves 0,1 ----
  if (wave < 2) {
    float s = 0.f;
#pragma unroll 8
    for (int j = 0; j < 32; ++j)
      s = fmaf(qtb[wave][kh * 32 + j][am], keb[wave][kh * 32 + j][am], s);
    s += __shfl_xor(s, 32, 64);
    if (kh == 0)
      ws[WS_L3 + (b * HS + y) * HS + wave * 32 + am] = s;
  }
}

// ---------------------------------------------------------------------------
// fullres v3: thread = 4 px (float4) x 4 ch; 16 ch-groups. Single HBM pass,
// ctx held in registers across softmax; two-stage LDS logit reduce.
// ---------------------------------------------------------------------------
__global__ __launch_bounds__(256) void fullres_kernel(
    const float* __restrict__ ctx, const float* __restrict__ ws,
    float* __restrict__ out) {
  const int xh = blockIdx.x & 1, hrow = blockIdx.x >> 1;
  const int b = blockIdx.y;
  const int quad = threadIdx.x & 15;       // 4-px group
  const int cg = threadIdx.x >> 4;         // 16 groups x 4 ch
  const int x = xh * 64 + quad * 4;
  const int h2 = hrow >> 1, w2 = (x >> 1); // w2, w2+1 for the two px pairs
  const int c0 = cg * 4;

  const size_t cbase = (size_t)(b * NCTX * CH) * FS * FS + hrow * FS + x;
  const int cs = FS * FS, ns = CH * FS * FS;

  // loads: ctx 12x dwordx4, qt 4x dwordx2
  float4 cv[3][4];
  float2 qv[4];
#pragma unroll
  for (int j = 0; j < 4; ++j) {
    const int c = c0 + j;
    cv[0][j] = *(const float4*)(ctx + cbase + c * cs);
    cv[1][j] = *(const float4*)(ctx + cbase + ns + c * cs);
    cv[2][j] = *(const float4*)(ctx + cbase + 2 * ns + c * cs);
    qv[j] = *(const float2*)(ws + WS_QT + (size_t)(b * CH + c) * HS * HS + h2 * HS + w2);
  }

  // partial logits for 4 px over this thread's 4 channels
  float4 pl[3];
#pragma unroll
  for (int n = 0; n < 3; ++n) {
    pl[n].x = pl[n].y = pl[n].z = pl[n].w = 0.f;
#pragma unroll
    for (int j = 0; j < 4; ++j) {
      pl[n].x = fmaf(cv[n][j].x, qv[j].x, pl[n].x);
      pl[n].y = fmaf(cv[n][j].y, qv[j].x, pl[n].y);
      pl[n].z = fmaf(cv[n][j].z, qv[j].y, pl[n].z);
      pl[n].w = fmaf(cv[n][j].w, qv[j].y, pl[n].w);
    }
  }

  __shared__ float4 part[3][16][17];       // padded: cg stride 68 floats
  __shared__ float  Lred[3][64];
#pragma unroll
  for (int n = 0; n < 3; ++n) part[n][cg][quad] = pl[n];
  __syncthreads();

  {
    const int tt = threadIdx.x;
    if (tt < 192) {
      const int n = tt >> 6, px = tt & 63;
      const float* pp = (const float*)part + (size_t)n * 16 * 17 * 4 + px;
      float s = 0.f;
#pragma unroll
      for (int g = 0; g < 16; ++g) s += pp[g * 68];
      Lred[n][px] = s;
    }
  }
  __syncthreads();

  float4 Lv0 = *(const float4*)&Lred[0][quad * 4];
  float4 Lv1 = *(const float4*)&Lred[1][quad * 4];
  float4 Lv2 = *(const float4*)&Lred[2][quad * 4];
  float2 l3v = *(const float2*)(ws + WS_L3 + (b * HS + h2) * HS + w2);

  float A0[4], A1[4], A2[4], A3[4];
  const float* L0p = (const float*)&Lv0;
  const float* L1p = (const float*)&Lv1;
  const float* L2p = (const float*)&Lv2;
#pragma unroll
  for (int k = 0; k < 4; ++k) {
    float L0 = L0p[k], L1 = L1p[k], L2 = L2p[k];
    float L3 = (k < 2) ? l3v.x : l3v.y;
    float mx = fmaxf(fmaxf(L0, L1), fmaxf(L2, L3));
    float e0 = __expf(L0 - mx), e1 = __expf(L1 - mx);
    float e2 = __expf(L2 - mx), e3 = __expf(L3 - mx);
    float inv = 1.f / (e0 + e1 + e2 + e3);
    A0[k] = e0 * inv; A1[k] = e1 * inv; A2[k] = e2 * inv; A3[k] = e3 * inv;
  }

  float* op = out + (size_t)(b * CH) * FS * FS + hrow * FS + x;
#pragma unroll
  for (int j = 0; j < 4; ++j) {
    const int c = c0 + j;
    float2 vv = *(const float2*)(ws + WS_VAL + (size_t)(b * CH + c) * HS * HS + h2 * HS + w2);
    float4 o;
    o.x = fmaf(A0[0], cv[0][j].x, fmaf(A1[0], cv[1][j].x, fmaf(A2[0], cv[2][j].x, A3[0] * vv.x)));
    o.y = fmaf(A0[1], cv[0][j].y, fmaf(A1[1], cv[1][j].y, fmaf(A2[1], cv[2][j].y, A3[1] * vv.x)));
    o.z = fmaf(A0[2], cv[0][j].z, fmaf(A1[2], cv[1][j].z, fmaf(A2[2], cv[2][j].z, A3[2] * vv.y)));
    o.w = fmaf(A0[3], cv[0][j].w, fmaf(A1[3], cv[1][j].w, fmaf(A2[3], cv[2][j].w, A3[3] * vv.y)));
    *(float4*)(op + c * cs) = o;
  }
}

// ---------------------------------------------------------------------------
extern "C" void kernel_launch(void* const* d_in, const int* in_sizes, int n_in,
                              void* d_out, int out_size, void* d_ws, size_t ws_size,
                              hipStream_t stream) {
  const float* ctx = (const float*)d_in[0];
  const float* ms  = (const float*)d_in[1];
  const float* Wc  = (const float*)d_in[2];
  // d_in[3] = bc : cancels in softmax
  const float* Wf  = (const float*)d_in[4];
  const float* bf  = (const float*)d_in[5];
  const float* Wk  = (const float*)d_in[6];
  const float* bk  = (const float*)d_in[7];
  const float* Vw  = (const float*)d_in[8];
  const float* Vb  = (const float*)d_in[9];
  float* ws  = (float*)d_ws;
  float* out = (float*)d_out;

  unsigned short* mth = (unsigned short*)(ws + WS_MTH);
  unsigned short* mtl = (unsigned short*)(ws + WS_MTL);

  setup_all<<<45 + NB * 66, 256, 0, stream>>>(Wc, Wf, bf, Wk, Vw, ms, ws);
  main_mfma<<<NB * HS, 1024, 0, stream>>>(mth, mtl, Vb, bk, ws);
  fullres_kernel<<<dim3(2 * FS, NB), 256, 0, stream>>>(ctx, ws, out);
}

// Round 6
// 247.812 us; speedup vs baseline: 2.5089x; 1.0204x over previous
//
#include <hip/hip_runtime.h>
#include <math.h>

// Problem constants
#define CH   64
#define FD   128
#define HS   64
#define FS   128
#define NB   8
#define NCTX 3

// workspace layout (float offsets)
#define WS_QT   0                       // qt  [B][64][64][64] fp32 (with bias)
#define WS_VAL  2097152                 // val [B][64][64][64] fp32
#define WS_L3   4194304                 // l3  [B][64][64]
#define WS_BQ   4227072                 // bq[64]
#define WS_AVH  4227136                 // conv A frags hi: [2][72][64][8] shorts
#define WS_AQH  4264000                 // qt A frags hi  : [2][8][64][8] shorts
#define WS_AQL  4268096
#define WS_AKH  4272192                 // key A frags
#define WS_AKL  4276288
// END 4280384 floats = 17.1 MB

typedef short  s16x8  __attribute__((ext_vector_type(8)));
typedef float  f32x16 __attribute__((ext_vector_type(16)));

__device__ inline unsigned short bf16_rne(float x) {
  unsigned u = __float_as_uint(x);
  u += 0x7FFFu + ((u >> 16) & 1u);
  return (unsigned short)(u >> 16);
}
__device__ inline void split2(float x, unsigned short& h, unsigned short& l) {
  h = bf16_rne(x);
  l = bf16_rne(x - __uint_as_float((unsigned)h << 16));
}

// ---------------------------------------------------------------------------
// afrag_prep: MFMA A-fragments (conv hi; qt/key hi+lo) + bq. 45 blocks.
// ---------------------------------------------------------------------------
__global__ __launch_bounds__(256) void afrag_prep(
    const float* __restrict__ Wc, const float* __restrict__ Wf,
    const float* __restrict__ bf, const float* __restrict__ Wk,
    const float* __restrict__ Vw, float* __restrict__ ws) {
  int id = blockIdx.x * 256 + threadIdx.x;
  unsigned short* avh = (unsigned short*)(ws + WS_AVH);
  unsigned short* aqh = (unsigned short*)(ws + WS_AQH);
  unsigned short* aql = (unsigned short*)(ws + WS_AQL);
  unsigned short* akh = (unsigned short*)(ws + WS_AKH);
  unsigned short* akl = (unsigned short*)(ws + WS_AKL);

  if (id < 9216) {                       // conv frags: hi only
    int tile = id / 4608, rem = id % 4608;
    int q = rem >> 6, l = rem & 63;
    int am = l & 31, kh = l >> 5;
    int c = tile * 32 + am, tap = q >> 3, kf = q & 7;
#pragma unroll
    for (int j = 0; j < 8; ++j) {
      int f = kf * 16 + kh * 8 + j;
      avh[id * 8 + j] = bf16_rne(Vw[(c * FD + f) * 9 + tap]);
    }
  } else if (id < 10240) {               // qt: Wq = Wc^T Wf inline
    int i2 = id - 9216;
    int tile = i2 >> 9, rem = i2 & 511;
    int q = rem >> 6, l = rem & 63;
    int am = l & 31, kh = l >> 5;
    int c = tile * 32 + am;
#pragma unroll
    for (int j = 0; j < 8; ++j) {
      int f = q * 16 + kh * 8 + j;
      float acc = 0.f;
      for (int d = 0; d < CH; ++d)
        acc = fmaf(Wc[d * CH + c], Wf[d * FD + f], acc);
      unsigned short h, lo; split2(acc, h, lo);
      aqh[i2 * 8 + j] = h; aql[i2 * 8 + j] = lo;
    }
  } else if (id < 11264) {               // keys: Wk direct
    int i3 = id - 10240;
    int tile = i3 >> 9, rem = i3 & 511;
    int q = rem >> 6, l = rem & 63;
    int am = l & 31, kh = l >> 5;
    int c = tile * 32 + am;
#pragma unroll
    for (int j = 0; j < 8; ++j) {
      int f = q * 16 + kh * 8 + j;
      unsigned short h, lo; split2(Wk[c * FD + f], h, lo);
      akh[i3 * 8 + j] = h; akl[i3 * 8 + j] = lo;
    }
  } else if (id < 11328) {               // bq = Wc^T bf
    int c = id - 11264;
    float acc = 0.f;
    for (int d = 0; d < CH; ++d) acc = fmaf(Wc[d * CH + c], bf[d], acc);
    ws[WS_BQ + c] = acc;
  }
}

// ---------------------------------------------------------------------------
// half_fused: one block per (b,y), 8 waves. Stage 3 m-rows to LDS in B-frag
// layout (hi bf16), then: waves 0-3 conv (full K, no split), waves 4-7 qt+keys
// (3-MFMA hi/lo split; B-lo recomputed from global m - staged hi) + l3 dot.
// ---------------------------------------------------------------------------
__global__ __launch_bounds__(512) void half_fused(
    const float* __restrict__ m, const float* __restrict__ Vb,
    const float* __restrict__ bk, float* __restrict__ ws) {
  const int b = blockIdx.x >> 6, y = blockIdx.x & 63;
  const int t = threadIdx.x, lane = t & 63;
  const int wave = __builtin_amdgcn_readfirstlane(t >> 6);
  const int am = lane & 31, kh = lane >> 5;

  // HI[row 0..2][kf][padded col 0..65][kh][8f]  (50688 B)
  __shared__ __align__(16) short HI[3][8][66][2][8];
  __shared__ float l3red[2][64];

  // ---- zero x-borders (cols 0 and 65), all rows/kf/kh ----
  if (t < 96) {
    int row = t / 32, kf = (t >> 2) & 7, khh = (t >> 1) & 1, col = (t & 1) * 65;
    s16x8 z;
#pragma unroll
    for (int j = 0; j < 8; ++j) z[j] = 0;
    *(s16x8*)&HI[row][kf][col][khh][0] = z;
  }

  // ---- stage hi: 48 wave-tasks (row,kf,kh), 6 per wave; coalesced reads ----
#pragma unroll
  for (int i = 0; i < 6; ++i) {
    const int tk = wave * 6 + i;               // 0..47
    const int row = tk >> 4, kf = (tk >> 1) & 7, khh = tk & 1;
    const int yy = y + row - 1;
    s16x8 hi;
    if (yy >= 0 && yy < HS) {
#pragma unroll
      for (int j = 0; j < 8; ++j) {
        const int f = kf * 16 + khh * 8 + j;
        hi[j] = (short)bf16_rne(m[((b * FD + f) * HS + yy) * HS + lane]);
      }
    } else {
#pragma unroll
      for (int j = 0; j < 8; ++j) hi[j] = 0;
    }
    *(s16x8*)&HI[row][kf][lane + 1][khh][0] = hi;
  }
  __syncthreads();

  float l3part = 0.f;
  if (wave < 4) {
    // ---- conv: tile (ct,xh), all 72 K-chunks, A-hi x B-hi ----
    const int ct = wave >> 1, xh = wave & 1;
    const int x0 = xh * 32, ch0 = ct * 32;
    const unsigned short* avh = (const unsigned short*)(ws + WS_AVH);
    f32x16 acc;
#pragma unroll
    for (int i = 0; i < 16; ++i) acc[i] = 0.f;
#pragma unroll 8
    for (int q = 0; q < 72; ++q) {
      const int tap = q >> 3, kf = q & 7;
      const s16x8 ah = *(const s16x8*)(avh + ((ct * 72 + q) * 64 + lane) * 8);
      const s16x8 bh = *(const s16x8*)&HI[tap / 3][kf][x0 + am + tap % 3][kh][0];
      acc = __builtin_amdgcn_mfma_f32_32x32x16_bf16(ah, bh, acc, 0, 0, 0);
    }
#pragma unroll
    for (int r = 0; r < 16; ++r) {
      const int c = ch0 + (r & 3) + 8 * (r >> 2) + 4 * kh;
      ws[WS_VAL + ((b * CH + c) * HS + y) * HS + x0 + am] = acc[r] + Vb[c];
    }
  } else {
    // ---- qt + keys: tile (ct,xh), K=128, 3-MFMA hi/lo split each ----
    const int w4 = wave - 4;
    const int ct = w4 >> 1, xh = w4 & 1;
    const int x0 = xh * 32, ch0 = ct * 32;
    const unsigned short* aqh = (const unsigned short*)(ws + WS_AQH);
    const unsigned short* aql = (const unsigned short*)(ws + WS_AQL);
    const unsigned short* akh = (const unsigned short*)(ws + WS_AKH);
    const unsigned short* akl = (const unsigned short*)(ws + WS_AKL);
    f32x16 q1, q2, k1, k2;
#pragma unroll
    for (int i = 0; i < 16; ++i) { q1[i] = 0.f; q2[i] = 0.f; k1[i] = 0.f; k2[i] = 0.f; }
#pragma unroll
    for (int q = 0; q < 8; ++q) {
      const s16x8 bh = *(const s16x8*)&HI[1][q][x0 + am + 1][kh][0];
      s16x8 bl;
#pragma unroll
      for (int j = 0; j < 8; ++j) {
        const float mv = m[((b * FD + q * 16 + kh * 8 + j) * HS + y) * HS + x0 + am];
        const float hf = __uint_as_float(((unsigned)(unsigned short)bh[j]) << 16);
        bl[j] = (short)bf16_rne(mv - hf);
      }
      const s16x8 ah = *(const s16x8*)(aqh + ((ct * 8 + q) * 64 + lane) * 8);
      const s16x8 al = *(const s16x8*)(aql + ((ct * 8 + q) * 64 + lane) * 8);
      const s16x8 kah = *(const s16x8*)(akh + ((ct * 8 + q) * 64 + lane) * 8);
      const s16x8 kal = *(const s16x8*)(akl + ((ct * 8 + q) * 64 + lane) * 8);
      q1 = __builtin_amdgcn_mfma_f32_32x32x16_bf16(ah, bh, q1, 0, 0, 0);
      q1 = __builtin_amdgcn_mfma_f32_32x32x16_bf16(al, bh, q1, 0, 0, 0);
      q2 = __builtin_amdgcn_mfma_f32_32x32x16_bf16(ah, bl, q2, 0, 0, 0);
      k1 = __builtin_amdgcn_mfma_f32_32x32x16_bf16(kah, bh, k1, 0, 0, 0);
      k1 = __builtin_amdgcn_mfma_f32_32x32x16_bf16(kal, bh, k1, 0, 0, 0);
      k2 = __builtin_amdgcn_mfma_f32_32x32x16_bf16(kah, bl, k2, 0, 0, 0);
    }
#pragma unroll
    for (int r = 0; r < 16; ++r) {
      const int c = ch0 + (r & 3) + 8 * (r >> 2) + 4 * kh;
      const float qv = q1[r] + q2[r] + ws[WS_BQ + c];
      const float kv = k1[r] + k2[r] + bk[c];
      ws[WS_QT + ((b * CH + c) * HS + y) * HS + x0 + am] = qv;
      l3part = fmaf(qv, kv, l3part);
    }
    if (ct == 1) l3red[xh][lane] = l3part;   // waves 6,7
  }
  __syncthreads();

  // ---- l3 = sum over all 64 ch: waves 4,5 (ct=0) finish ----
  if (wave == 4 || wave == 5) {
    const int xh = wave - 4;
    float s = l3part + l3red[xh][lane];
    s += __shfl_xor(s, 32, 64);
    if (kh == 0)
      ws[WS_L3 + (b * HS + y) * HS + xh * 32 + am] = s;
  }
}

// ---------------------------------------------------------------------------
// fullres v3 (unchanged): thread = 4 px x 4 ch; single HBM pass over ctx,
// ctx in registers across softmax; two-stage LDS logit reduce.
// ---------------------------------------------------------------------------
__global__ __launch_bounds__(256) void fullres_kernel(
    const float* __restrict__ ctx, const float* __restrict__ ws,
    float* __restrict__ out) {
  const int xh = blockIdx.x & 1, hrow = blockIdx.x >> 1;
  const int b = blockIdx.y;
  const int quad = threadIdx.x & 15;
  const int cg = threadIdx.x >> 4;
  const int x = xh * 64 + quad * 4;
  const int h2 = hrow >> 1, w2 = (x >> 1);
  const int c0 = cg * 4;

  const size_t cbase = (size_t)(b * NCTX * CH) * FS * FS + hrow * FS + x;
  const int cs = FS * FS, ns = CH * FS * FS;

  float4 cv[3][4];
  float2 qv[4];
#pragma unroll
  for (int j = 0; j < 4; ++j) {
    const int c = c0 + j;
    cv[0][j] = *(const float4*)(ctx + cbase + c * cs);
    cv[1][j] = *(const float4*)(ctx + cbase + ns + c * cs);
    cv[2][j] = *(const float4*)(ctx + cbase + 2 * ns + c * cs);
    qv[j] = *(const float2*)(ws + WS_QT + (size_t)(b * CH + c) * HS * HS + h2 * HS + w2);
  }

  float4 pl[3];
#pragma unroll
  for (int n = 0; n < 3; ++n) {
    pl[n].x = pl[n].y = pl[n].z = pl[n].w = 0.f;
#pragma unroll
    for (int j = 0; j < 4; ++j) {
      pl[n].x = fmaf(cv[n][j].x, qv[j].x, pl[n].x);
      pl[n].y = fmaf(cv[n][j].y, qv[j].x, pl[n].y);
      pl[n].z = fmaf(cv[n][j].z, qv[j].y, pl[n].z);
      pl[n].w = fmaf(cv[n][j].w, qv[j].y, pl[n].w);
    }
  }

  __shared__ float4 part[3][16][17];
  __shared__ float  Lred[3][64];
#pragma unroll
  for (int n = 0; n < 3; ++n) part[n][cg][quad] = pl[n];
  __syncthreads();

  {
    const int tt = threadIdx.x;
    if (tt < 192) {
      const int n = tt >> 6, px = tt & 63;
      const float* pp = (const float*)part + (size_t)n * 16 * 17 * 4 + px;
      float s = 0.f;
#pragma unroll
      for (int g = 0; g < 16; ++g) s += pp[g * 68];
      Lred[n][px] = s;
    }
  }
  __syncthreads();

  float4 Lv0 = *(const float4*)&Lred[0][quad * 4];
  float4 Lv1 = *(const float4*)&Lred[1][quad * 4];
  float4 Lv2 = *(const float4*)&Lred[2][quad * 4];
  float2 l3v = *(const float2*)(ws + WS_L3 + (b * HS + h2) * HS + w2);

  float A0[4], A1[4], A2[4], A3[4];
  const float* L0p = (const float*)&Lv0;
  const float* L1p = (const float*)&Lv1;
  const float* L2p = (const float*)&Lv2;
#pragma unroll
  for (int k = 0; k < 4; ++k) {
    float L0 = L0p[k], L1 = L1p[k], L2 = L2p[k];
    float L3 = (k < 2) ? l3v.x : l3v.y;
    float mx = fmaxf(fmaxf(L0, L1), fmaxf(L2, L3));
    float e0 = __expf(L0 - mx), e1 = __expf(L1 - mx);
    float e2 = __expf(L2 - mx), e3 = __expf(L3 - mx);
    float inv = 1.f / (e0 + e1 + e2 + e3);
    A0[k] = e0 * inv; A1[k] = e1 * inv; A2[k] = e2 * inv; A3[k] = e3 * inv;
  }

  float* op = out + (size_t)(b * CH) * FS * FS + hrow * FS + x;
#pragma unroll
  for (int j = 0; j < 4; ++j) {
    const int c = c0 + j;
    float2 vv = *(const float2*)(ws + WS_VAL + (size_t)(b * CH + c) * HS * HS + h2 * HS + w2);
    float4 o;
    o.x = fmaf(A0[0], cv[0][j].x, fmaf(A1[0], cv[1][j].x, fmaf(A2[0], cv[2][j].x, A3[0] * vv.x)));
    o.y = fmaf(A0[1], cv[0][j].y, fmaf(A1[1], cv[1][j].y, fmaf(A2[1], cv[2][j].y, A3[1] * vv.x)));
    o.z = fmaf(A0[2], cv[0][j].z, fmaf(A1[2], cv[1][j].z, fmaf(A2[2], cv[2][j].z, A3[2] * vv.y)));
    o.w = fmaf(A0[3], cv[0][j].w, fmaf(A1[3], cv[1][j].w, fmaf(A2[3], cv[2][j].w, A3[3] * vv.y)));
    *(float4*)(op + c * cs) = o;
  }
}

// ---------------------------------------------------------------------------
extern "C" void kernel_launch(void* const* d_in, const int* in_sizes, int n_in,
                              void* d_out, int out_size, void* d_ws, size_t ws_size,
                              hipStream_t stream) {
  const float* ctx = (const float*)d_in[0];
  const float* ms  = (const float*)d_in[1];
  const float* Wc  = (const float*)d_in[2];
  // d_in[3] = bc : cancels in softmax
  const float* Wf  = (const float*)d_in[4];
  const float* bf  = (const float*)d_in[5];
  const float* Wk  = (const float*)d_in[6];
  const float* bk  = (const float*)d_in[7];
  const float* Vw  = (const float*)d_in[8];
  const float* Vb  = (const float*)d_in[9];
  float* ws  = (float*)d_ws;
  float* out = (float*)d_out;

  afrag_prep<<<45, 256, 0, stream>>>(Wc, Wf, bf, Wk, Vw, ws);
  half_fused<<<NB * HS, 512, 0, stream>>>(ms, Vb, bk, ws);
  fullres_kernel<<<dim3(2 * FS, NB), 256, 0, stream>>>(ctx, ws, out);
}